// Round 20
// baseline (171.947 us; speedup 1.0000x reference)
//
#include <hip/hip_runtime.h>

constexpr int NN = 50000;   // nodes
constexpr int NE = 800000;  // edges
constexpr int NG = 64;      // graphs
constexpr int DI = 64;      // in dim
constexpr int DH = 128;     // hidden dim
constexpr int DO = 3;       // out dim

constexpr int SCAN_B = 256;
constexpr int NBK = 196;                  // dst buckets of 256 nodes (dst >> 8)
constexpr int CHUNK = 4096;               // edges per partition block
constexpr int NCH = (NE + CHUNK - 1) / CHUNK;  // 196 chunks
constexpr int BBTOT = NBK * NCH;          // 38416 (bucket-major [b][c])
constexpr int NBB = (BBTOT + 255) / 256;  // 151 scan blocks

typedef unsigned int u32;

// ---------------- bf16 helpers ----------------
__device__ inline float blo(u32 u) { return __uint_as_float(u << 16); }
__device__ inline float bhi(u32 u) { return __uint_as_float(u & 0xffff0000u); }
__device__ inline u32 f2b(float f) {  // RNE round to bf16 (16-bit pattern)
    u32 u = __float_as_uint(f);
    return (u + 0x7fffu + ((u >> 16) & 1u)) >> 16;
}
__device__ inline void fma8(float w, uint4 v, float acc[8]) {
    acc[0] = fmaf(w, blo(v.x), acc[0]); acc[1] = fmaf(w, bhi(v.x), acc[1]);
    acc[2] = fmaf(w, blo(v.y), acc[2]); acc[3] = fmaf(w, bhi(v.y), acc[3]);
    acc[4] = fmaf(w, blo(v.z), acc[4]); acc[5] = fmaf(w, bhi(v.z), acc[5]);
    acc[6] = fmaf(w, blo(v.w), acc[6]); acc[7] = fmaf(w, bhi(v.w), acc[7]);
}

// ---------------- fused: x->bf16, zero pooled, gstart bsearch ----------------
__global__ void k_init(const float* __restrict__ x, uint4* __restrict__ xb,
                       float* __restrict__ pooled, const int* __restrict__ batch,
                       int* __restrict__ gstart) {
    int i = blockIdx.x * blockDim.x + threadIdx.x;
    if (i < NN * DI / 8) {
        float4 a = reinterpret_cast<const float4*>(x)[i * 2];
        float4 b = reinterpret_cast<const float4*>(x)[i * 2 + 1];
        uint4 o;
        o.x = f2b(a.x) | (f2b(a.y) << 16);
        o.y = f2b(a.z) | (f2b(a.w) << 16);
        o.z = f2b(b.x) | (f2b(b.y) << 16);
        o.w = f2b(b.z) | (f2b(b.w) << 16);
        xb[i] = o;
    }
    if (i < NG * DH) pooled[i] = 0.0f;
    if (blockIdx.x == 0 && threadIdx.x <= NG) {
        int g = threadIdx.x;
        int lo = 0, hi = NN;
        while (lo < hi) {
            int mid = (lo + hi) >> 1;
            if (batch[mid] < g) lo = mid + 1; else hi = mid;
        }
        gstart[g] = lo;
    }
}

// ---------------- hist: per-(bucket,chunk) LDS counts ONLY (no global atomics) ----------------
__global__ __launch_bounds__(256) void k_histc(const int* __restrict__ dst,
                                               int* __restrict__ cntBB) {
    __shared__ int lcnt[NBK];
    const int t = threadIdx.x, c = blockIdx.x;
    for (int b = t; b < NBK; b += 256) lcnt[b] = 0;
    __syncthreads();
    const int base = c * CHUNK;
    const int endE = min(base + CHUNK, NE);
    for (int e = base + t; e < endE; e += 256) atomicAdd(&lcnt[dst[e] >> 8], 1);
    __syncthreads();
    for (int b = t; b < NBK; b += 256) cntBB[b * NCH + c] = lcnt[b];
}

// block-local inclusive scan helper over sm[256]
__device__ inline void blockScan(int* sm) {
    for (int off = 1; off < SCAN_B; off <<= 1) {
        int add = (threadIdx.x >= off) ? sm[threadIdx.x - off] : 0;
        __syncthreads();
        sm[threadIdx.x] += add;
        __syncthreads();
    }
}

// ---------------- cntBB block scans (in place) + per-block sums ----------------
__global__ void k_scanBB1(int* __restrict__ cntBB, int* __restrict__ bbpartial) {
    __shared__ int sm[SCAN_B];
    int i = blockIdx.x * SCAN_B + threadIdx.x;
    int v = (i < BBTOT) ? cntBB[i] : 0;
    sm[threadIdx.x] = v;
    __syncthreads();
    blockScan(sm);
    if (i < BBTOT) cntBB[i] = sm[threadIdx.x] - v;  // block-local exclusive
    if (threadIdx.x == SCAN_B - 1) bbpartial[blockIdx.x] = sm[SCAN_B - 1];
}

__global__ void k_scanB(int* __restrict__ bbpartial) {  // single block, NBB<=256
    __shared__ int sm[SCAN_B];
    int v = (threadIdx.x < NBB) ? bbpartial[threadIdx.x] : 0;
    sm[threadIdx.x] = v;
    __syncthreads();
    blockScan(sm);
    if (threadIdx.x < NBB) bbpartial[threadIdx.x] = sm[threadIdx.x] - v;  // exclusive
}

// ---------------- pass 2: bin (src | dst&255) into bucket-sorted stage via LDS cursors ----------------
__global__ __launch_bounds__(256) void k_fillP2(const int* __restrict__ src,
                                                const int* __restrict__ dst,
                                                const int* __restrict__ cntBB,
                                                const int* __restrict__ bbpartial,
                                                u32* __restrict__ stage) {
    __shared__ int lcur[NBK];
    const int t = threadIdx.x, c = blockIdx.x;
    for (int b = t; b < NBK; b += 256) {
        int i = b * NCH + c;
        lcur[b] = cntBB[i] + bbpartial[i >> 8];
    }
    __syncthreads();
    const int base = c * CHUNK;
    const int endE = min(base + CHUNK, NE);
    for (int e = base + t; e < endE; e += 256) {
        int s = src[e], d = dst[e];
        int slot = atomicAdd(&lcur[d >> 8], 1);
        stage[slot] = ((u32)(d & 255) << 16) | (u32)s;
    }
}

// ---------------- pass B: per-bucket LDS counting sort -> rowptr, dinv, csr16 ----------------
__global__ __launch_bounds__(256) void k_fillB(const u32* __restrict__ stage,
                                               const int* __restrict__ cntBB,
                                               const int* __restrict__ bbpartial,
                                               int* __restrict__ rowptr,
                                               float* __restrict__ dinv,
                                               ushort* __restrict__ csr16) {
    __shared__ int cnt[256];
    __shared__ int sm[256];
    __shared__ int cur[256];
    const int b = blockIdx.x, t = threadIdx.x;
    cnt[t] = 0;
    const int i0 = b * NCH;
    const int beg = cntBB[i0] + bbpartial[i0 >> 8];
    const int end = (b + 1 < NBK) ? cntBB[i0 + NCH] + bbpartial[(i0 + NCH) >> 8] : NE;
    __syncthreads();
    for (int i = beg + t; i < end; i += 256) atomicAdd(&cnt[(stage[i] >> 16) & 255u], 1);
    __syncthreads();
    const int v = cnt[t];
    sm[t] = v;
    __syncthreads();
    blockScan(sm);
    const int excl = sm[t] - v;
    const int n = b * 256 + t;
    if (n < NN) {
        rowptr[n] = beg + excl;
        dinv[n] = rsqrtf((float)(v + 1));  // +1 self-loop
    }
    if (b == NBK - 1 && t == 0) rowptr[NN] = NE;
    cur[t] = beg + excl;
    __syncthreads();
    for (int i = beg + t; i < end; i += 256) {
        u32 e = stage[i];
        int slot = atomicAdd(&cur[(e >> 16) & 255u], 1);
        csr16[slot] = (ushort)(e & 0xffffu);
    }
}

// ---------------- gather aggregation (zero LDS, high occupancy): u16 csr, w from dinv ----------------
template <int D, bool BIAS_RELU>
__global__ __launch_bounds__(256) void k_agge(const ushort* __restrict__ hb,
                                              const ushort* __restrict__ csr16,
                                              const int* __restrict__ rowptr,
                                              const float* __restrict__ dinv,
                                              const float* __restrict__ bias,
                                              u32* __restrict__ out) {
    constexpr int SUB = D / 8;        // lanes per node (8 for D=64, 16 for D=128)
    constexpr int NPB = 256 / SUB;    // nodes per block
    const int sub = threadIdx.x / SUB;
    const int sl = threadIdx.x % SUB;
    const int node = blockIdx.x * NPB + sub;
    if (node >= NN) return;

    const float dn = dinv[node];
    float acc[8];
    {
        uint4 v = *reinterpret_cast<const uint4*>(hb + (size_t)node * D + sl * 8);
        float w = dn * dn;
        acc[0] = w * blo(v.x); acc[1] = w * bhi(v.x);
        acc[2] = w * blo(v.y); acc[3] = w * bhi(v.y);
        acc[4] = w * blo(v.z); acc[5] = w * bhi(v.z);
        acc[6] = w * blo(v.w); acc[7] = w * bhi(v.w);
    }
    int j = rowptr[node];
    const int end = rowptr[node + 1];
    while ((j & 3) && j < end) {
        int s = csr16[j];
        uint4 g = *reinterpret_cast<const uint4*>(hb + (size_t)s * D + sl * 8);
        fma8(dn * dinv[s], g, acc);
        ++j;
    }
    for (; j + 4 <= end; j += 4) {
        ushort4 q = *reinterpret_cast<const ushort4*>(csr16 + j);
        uint4 g0 = *reinterpret_cast<const uint4*>(hb + (size_t)q.x * D + sl * 8);
        uint4 g1 = *reinterpret_cast<const uint4*>(hb + (size_t)q.y * D + sl * 8);
        uint4 g2 = *reinterpret_cast<const uint4*>(hb + (size_t)q.z * D + sl * 8);
        uint4 g3 = *reinterpret_cast<const uint4*>(hb + (size_t)q.w * D + sl * 8);
        float w0 = dn * dinv[q.x], w1 = dn * dinv[q.y];
        float w2 = dn * dinv[q.z], w3 = dn * dinv[q.w];
        fma8(w0, g0, acc);
        fma8(w1, g1, acc);
        fma8(w2, g2, acc);
        fma8(w3, g3, acc);
    }
    while (j < end) {
        int s = csr16[j];
        uint4 g = *reinterpret_cast<const uint4*>(hb + (size_t)s * D + sl * 8);
        fma8(dn * dinv[s], g, acc);
        ++j;
    }
    if (BIAS_RELU) {
        float4 b0 = *reinterpret_cast<const float4*>(bias + sl * 8);
        float4 b1v = *reinterpret_cast<const float4*>(bias + sl * 8 + 4);
        acc[0] = fmaxf(acc[0] + b0.x, 0.f); acc[1] = fmaxf(acc[1] + b0.y, 0.f);
        acc[2] = fmaxf(acc[2] + b0.z, 0.f); acc[3] = fmaxf(acc[3] + b0.w, 0.f);
        acc[4] = fmaxf(acc[4] + b1v.x, 0.f); acc[5] = fmaxf(acc[5] + b1v.y, 0.f);
        acc[6] = fmaxf(acc[6] + b1v.z, 0.f); acc[7] = fmaxf(acc[7] + b1v.w, 0.f);
    }
    uint4 o;
    o.x = f2b(acc[0]) | (f2b(acc[1]) << 16);
    o.y = f2b(acc[2]) | (f2b(acc[3]) << 16);
    o.z = f2b(acc[4]) | (f2b(acc[5]) << 16);
    o.w = f2b(acc[6]) | (f2b(acc[7]) << 16);
    *reinterpret_cast<uint4*>(reinterpret_cast<ushort*>(out) + (size_t)node * D + sl * 8) = o;
}

// ---------------- FUSED double GEMM, direct-global W reads (L1/L2-resident), 3 barriers ----------------
// agg1b bf16 -> GEMM1(W1 direct)+b1+relu -> (h1 bf16 in LDS union) -> GEMM2(W2 direct) -> tb bf16
__device__ inline float4 fmaf4(float s, float4 w, float4 a) {
    a.x = fmaf(s, w.x, a.x); a.y = fmaf(s, w.y, a.y);
    a.z = fmaf(s, w.z, a.z); a.w = fmaf(s, w.w, a.w);
    return a;
}

__global__ __launch_bounds__(256) void k_gemm12(const ushort* __restrict__ A,
                                                const float* __restrict__ W1,
                                                const float* __restrict__ b1,
                                                const float* __restrict__ W2,
                                                u32* __restrict__ T) {
    constexpr int ASTR = 72;     // sA bf16 row stride (ushorts)
    __shared__ ushort sU16[64 * DH];  // 16 KB union: sA bf16 [64][72] then sH bf16 [64][128]
    const int t = threadIdx.x;
    const int row0 = blockIdx.x * 64;
    const int cg = t & 31;
    const int rg = t >> 5;

    // ---- stage A (bf16, straight copy): 64 rows x 64 cols
    {
        const int row = t >> 2;      // 0..63
        const int q = t & 3;         // 16-ushort quarter
        int gr = row0 + row;
        uint4 v0 = make_uint4(0u, 0u, 0u, 0u), v1 = v0;
        if (gr < NN) {
            const uint4* Ag = reinterpret_cast<const uint4*>(A + (size_t)gr * DI + q * 16);
            v0 = Ag[0];
            v1 = Ag[1];
        }
        *reinterpret_cast<uint4*>(&sU16[row * ASTR + q * 16]) = v0;
        *reinterpret_cast<uint4*>(&sU16[row * ASTR + q * 16 + 8]) = v1;
    }
    __syncthreads();

    // ---- GEMM1: K=64, W1 read direct from global (cache-resident), +b1, relu
    const float* W1c = W1 + cg * 4;  // column slice base
    float4 acc[8];
#pragma unroll
    for (int j = 0; j < 8; ++j) acc[j] = make_float4(0.f, 0.f, 0.f, 0.f);

#pragma unroll 4
    for (int kk = 0; kk < DI; kk += 4) {
        float4 w0 = *reinterpret_cast<const float4*>(W1c + (kk + 0) * DH);
        float4 w1 = *reinterpret_cast<const float4*>(W1c + (kk + 1) * DH);
        float4 w2 = *reinterpret_cast<const float4*>(W1c + (kk + 2) * DH);
        float4 w3 = *reinterpret_cast<const float4*>(W1c + (kk + 3) * DH);
#pragma unroll
        for (int j = 0; j < 8; ++j) {
            uint2 av = *reinterpret_cast<const uint2*>(&sU16[(rg * 8 + j) * ASTR + kk]);
            acc[j] = fmaf4(blo(av.x), w0, acc[j]);
            acc[j] = fmaf4(bhi(av.x), w1, acc[j]);
            acc[j] = fmaf4(blo(av.y), w2, acc[j]);
            acc[j] = fmaf4(bhi(av.y), w3, acc[j]);
        }
    }
    {
        float4 bb = *reinterpret_cast<const float4*>(b1 + cg * 4);
#pragma unroll
        for (int j = 0; j < 8; ++j) {
            acc[j].x = fmaxf(acc[j].x + bb.x, 0.f);
            acc[j].y = fmaxf(acc[j].y + bb.y, 0.f);
            acc[j].z = fmaxf(acc[j].z + bb.z, 0.f);
            acc[j].w = fmaxf(acc[j].w + bb.w, 0.f);
        }
    }

    // ---- h1 (bf16) -> sH (same union; all sA reads complete first)
    __syncthreads();
#pragma unroll
    for (int j = 0; j < 8; ++j) {
        uint2 o = make_uint2(f2b(acc[j].x) | (f2b(acc[j].y) << 16),
                             f2b(acc[j].z) | (f2b(acc[j].w) << 16));
        *reinterpret_cast<uint2*>(&sU16[(rg * 8 + j) * DH + cg * 4]) = o;
    }
    __syncthreads();

    // ---- GEMM2: K=128, W2 direct -> tb bf16
    const float* W2c = W2 + cg * 4;
    float4 acc2[8];
#pragma unroll
    for (int j = 0; j < 8; ++j) acc2[j] = make_float4(0.f, 0.f, 0.f, 0.f);

#pragma unroll 4
    for (int kk = 0; kk < DH; kk += 4) {
        float4 w0 = *reinterpret_cast<const float4*>(W2c + (kk + 0) * DH);
        float4 w1 = *reinterpret_cast<const float4*>(W2c + (kk + 1) * DH);
        float4 w2 = *reinterpret_cast<const float4*>(W2c + (kk + 2) * DH);
        float4 w3 = *reinterpret_cast<const float4*>(W2c + (kk + 3) * DH);
#pragma unroll
        for (int j = 0; j < 8; ++j) {
            uint2 av = *reinterpret_cast<const uint2*>(&sU16[(rg * 8 + j) * DH + kk]);
            acc2[j] = fmaf4(blo(av.x), w0, acc2[j]);
            acc2[j] = fmaf4(bhi(av.x), w1, acc2[j]);
            acc2[j] = fmaf4(blo(av.y), w2, acc2[j]);
            acc2[j] = fmaf4(bhi(av.y), w3, acc2[j]);
        }
    }
#pragma unroll
    for (int j = 0; j < 8; ++j) {
        int gr = row0 + rg * 8 + j;
        if (gr < NN) {
            uint2 o = make_uint2(f2b(acc2[j].x) | (f2b(acc2[j].y) << 16),
                                 f2b(acc2[j].z) | (f2b(acc2[j].w) << 16));
            *reinterpret_cast<uint2*>(&T[(size_t)gr * (DH / 2) + cg * 2]) = o;
        }
    }
}

// ---------------- pooling (bf16 input, coalesced u32 reads) ----------------
constexpr int POOL_CHUNK = 64;
__global__ __launch_bounds__(256) void k_pool3(const u32* __restrict__ h2b,
                                               const int* __restrict__ batch,
                                               float* __restrict__ pooled) {
    const int c2 = threadIdx.x & 63;
    const int q = threadIdx.x >> 6;
    const int n0 = blockIdx.x * POOL_CHUNK;
    const int nEnd = min(n0 + POOL_CHUNK, NN);
    float a0 = 0.f, a1 = 0.f;
    int gcur = -1;
    for (int n = n0 + q; n < nEnd; n += 4) {
        int g = batch[n];
        if (g != gcur) {
            if (gcur >= 0) {
                atomicAdd(&pooled[gcur * DH + c2 * 2], a0);
                atomicAdd(&pooled[gcur * DH + c2 * 2 + 1], a1);
            }
            a0 = a1 = 0.f;
            gcur = g;
        }
        u32 v = h2b[(size_t)n * (DH / 2) + c2];
        a0 += blo(v);
        a1 += bhi(v);
    }
    if (gcur >= 0) {
        atomicAdd(&pooled[gcur * DH + c2 * 2], a0);
        atomicAdd(&pooled[gcur * DH + c2 * 2 + 1], a1);
    }
}

__global__ void k_head(const float* __restrict__ pooled, const int* __restrict__ gstart,
                       const float* __restrict__ Wf, const float* __restrict__ bf,
                       float* __restrict__ out) {
    int t = threadIdx.x;
    if (t >= NG * DO) return;
    int g = t / DO, o = t - g * DO;
    float acc = 0.0f;
    for (int k = 0; k < DH; ++k) acc += pooled[g * DH + k] * Wf[k * DO + o];
    float cnt = fmaxf((float)(gstart[g + 1] - gstart[g]), 1.0f);
    out[t] = acc / cnt + bf[o];
}

extern "C" void kernel_launch(void* const* d_in, const int* in_sizes, int n_in,
                              void* d_out, int out_size, void* d_ws, size_t ws_size,
                              hipStream_t stream) {
    const float* x   = (const float*)d_in[0];
    const int* ei    = (const int*)d_in[1];  // [2, NE] row-major
    const int* batch = (const int*)d_in[2];
    const float* W1  = (const float*)d_in[3];
    const float* b1  = (const float*)d_in[4];
    const float* W2  = (const float*)d_in[5];
    const float* b2  = (const float*)d_in[6];
    const float* Wf  = (const float*)d_in[7];
    const float* bf  = (const float*)d_in[8];
    float* out = (float*)d_out;

    const int* src = ei;
    const int* dst = ei + NE;

    // workspace (4B units; ~44 MB total)
    int* rowptr    = (int*)d_ws;               // 50056 (NN+1 used)
    int* bbpartial = rowptr + 50056;           // 256
    int* gstart    = bbpartial + 256;          // 80
    int* cntBB     = gstart + 80;              // 38416 ([b][c] bucket-major)
    ushort* csr16  = (ushort*)(cntBB + 38416); // NE u16 = 400000 u32
    float* dinv    = (float*)((u32*)(cntBB + 38416) + 400000);  // 50048
    u32* xbu       = (u32*)(dinv + 50048);     // 1.6M u32 (NN x 64 bf16)
    u32* stage     = xbu + 1600000;            // 0.8M u32 (NE packed entries)
    u32* agg1bu    = stage + 800000;           // 1.6M u32 (NN x 64 bf16)
    u32* tbu       = agg1bu + 1600000;         // 3.2M u32 (NN x 128 bf16)
    u32* h2b       = tbu + 3200000;            // 3.2M u32 (NN x 128 bf16)
    float* pooled  = (float*)(h2b + 3200000);  // 8192

    ushort* xb    = (ushort*)xbu;
    ushort* agg1b = (ushort*)agg1bu;
    ushort* tb    = (ushort*)tbu;

    const int B = 256;
    k_init<<<(NN * DI / 8 + B - 1) / B, B, 0, stream>>>(x, (uint4*)xb, pooled, batch, gstart);
    k_histc<<<NCH, 256, 0, stream>>>(dst, cntBB);
    k_scanBB1<<<NBB, SCAN_B, 0, stream>>>(cntBB, bbpartial);
    k_scanB<<<1, SCAN_B, 0, stream>>>(bbpartial);
    k_fillP2<<<NCH, 256, 0, stream>>>(src, dst, cntBB, bbpartial, stage);
    k_fillB<<<NBK, 256, 0, stream>>>(stage, cntBB, bbpartial, rowptr, dinv, csr16);

    const int gemmGrid = (NN + 63) / 64;  // 782

    // layer 1 agg (zero-LDS, high occupancy): gather xb -> agg1b bf16
    k_agge<DI, false><<<(NN + 31) / 32, 256, 0, stream>>>(xb, csr16, rowptr, dinv,
                                                          nullptr, agg1bu);
    // fused GEMM1+GEMM2 (direct-global W, 16KB LDS, 3 barriers): agg1b -> h1 -> tb
    k_gemm12<<<gemmGrid, 256, 0, stream>>>(agg1b, W1, b1, W2, tbu);

    // layer-2 agg: gather tb, +b2, relu -> h2b (bf16)
    k_agge<DH, true><<<(NN + 15) / 16, 256, 0, stream>>>(tb, csr16, rowptr, dinv, b2, h2b);

    // pool + head
    k_pool3<<<(NN + POOL_CHUNK - 1) / POOL_CHUNK, 256, 0, stream>>>(h2b, batch, pooled);
    k_head<<<1, 256, 0, stream>>>(pooled, gstart, Wf, bf, out);
}

// Round 21
// 171.452 us; speedup vs baseline: 1.0029x; 1.0029x over previous
//
#include <hip/hip_runtime.h>

constexpr int NN = 50000;   // nodes
constexpr int NE = 800000;  // edges
constexpr int NG = 64;      // graphs
constexpr int DI = 64;      // in dim
constexpr int DH = 128;     // hidden dim
constexpr int DO = 3;       // out dim

constexpr int SCAN_B = 256;
constexpr int NBK = 196;                  // dst buckets of 256 nodes (dst >> 8)
constexpr int CHUNK = 4096;               // edges per partition block
constexpr int NCH = (NE + CHUNK - 1) / CHUNK;  // 196 chunks
constexpr int BBTOT = NBK * NCH;          // 38416 (bucket-major [b][c])
constexpr int NBB = (BBTOT + 255) / 256;  // 151 scan blocks

typedef unsigned int u32;

// ---------------- bf16 helpers ----------------
__device__ inline float blo(u32 u) { return __uint_as_float(u << 16); }
__device__ inline float bhi(u32 u) { return __uint_as_float(u & 0xffff0000u); }
__device__ inline u32 f2b(float f) {  // RNE round to bf16 (16-bit pattern)
    u32 u = __float_as_uint(f);
    return (u + 0x7fffu + ((u >> 16) & 1u)) >> 16;
}
__device__ inline void fma8(float w, uint4 v, float acc[8]) {
    acc[0] = fmaf(w, blo(v.x), acc[0]); acc[1] = fmaf(w, bhi(v.x), acc[1]);
    acc[2] = fmaf(w, blo(v.y), acc[2]); acc[3] = fmaf(w, bhi(v.y), acc[3]);
    acc[4] = fmaf(w, blo(v.z), acc[4]); acc[5] = fmaf(w, bhi(v.z), acc[5]);
    acc[6] = fmaf(w, blo(v.w), acc[6]); acc[7] = fmaf(w, bhi(v.w), acc[7]);
}

// ---------------- fused: x->bf16, zero pooled, gstart bsearch ----------------
__global__ void k_init(const float* __restrict__ x, uint4* __restrict__ xb,
                       float* __restrict__ pooled, const int* __restrict__ batch,
                       int* __restrict__ gstart) {
    int i = blockIdx.x * blockDim.x + threadIdx.x;
    if (i < NN * DI / 8) {
        float4 a = reinterpret_cast<const float4*>(x)[i * 2];
        float4 b = reinterpret_cast<const float4*>(x)[i * 2 + 1];
        uint4 o;
        o.x = f2b(a.x) | (f2b(a.y) << 16);
        o.y = f2b(a.z) | (f2b(a.w) << 16);
        o.z = f2b(b.x) | (f2b(b.y) << 16);
        o.w = f2b(b.z) | (f2b(b.w) << 16);
        xb[i] = o;
    }
    if (i < NG * DH) pooled[i] = 0.0f;
    if (blockIdx.x == 0 && threadIdx.x <= NG) {
        int g = threadIdx.x;
        int lo = 0, hi = NN;
        while (lo < hi) {
            int mid = (lo + hi) >> 1;
            if (batch[mid] < g) lo = mid + 1; else hi = mid;
        }
        gstart[g] = lo;
    }
}

// ---------------- hist: per-(bucket,chunk) LDS counts ONLY (no global atomics) ----------------
__global__ __launch_bounds__(256) void k_histc(const int* __restrict__ dst,
                                               int* __restrict__ cntBB) {
    __shared__ int lcnt[NBK];
    const int t = threadIdx.x, c = blockIdx.x;
    for (int b = t; b < NBK; b += 256) lcnt[b] = 0;
    __syncthreads();
    const int base = c * CHUNK;
    const int endE = min(base + CHUNK, NE);
    for (int e = base + t; e < endE; e += 256) atomicAdd(&lcnt[dst[e] >> 8], 1);
    __syncthreads();
    for (int b = t; b < NBK; b += 256) cntBB[b * NCH + c] = lcnt[b];
}

// block-local inclusive scan helper over sm[256]
__device__ inline void blockScan(int* sm) {
    for (int off = 1; off < SCAN_B; off <<= 1) {
        int add = (threadIdx.x >= off) ? sm[threadIdx.x - off] : 0;
        __syncthreads();
        sm[threadIdx.x] += add;
        __syncthreads();
    }
}

// ---------------- cntBB block scans (in place) + per-block sums ----------------
__global__ void k_scanBB1(int* __restrict__ cntBB, int* __restrict__ bbpartial) {
    __shared__ int sm[SCAN_B];
    int i = blockIdx.x * SCAN_B + threadIdx.x;
    int v = (i < BBTOT) ? cntBB[i] : 0;
    sm[threadIdx.x] = v;
    __syncthreads();
    blockScan(sm);
    if (i < BBTOT) cntBB[i] = sm[threadIdx.x] - v;  // block-local exclusive
    if (threadIdx.x == SCAN_B - 1) bbpartial[blockIdx.x] = sm[SCAN_B - 1];
}

__global__ void k_scanB(int* __restrict__ bbpartial) {  // single block, NBB<=256
    __shared__ int sm[SCAN_B];
    int v = (threadIdx.x < NBB) ? bbpartial[threadIdx.x] : 0;
    sm[threadIdx.x] = v;
    __syncthreads();
    blockScan(sm);
    if (threadIdx.x < NBB) bbpartial[threadIdx.x] = sm[threadIdx.x] - v;  // exclusive
}

// ---------------- pass 2: bin (src | dst&255) into bucket-sorted stage via LDS cursors ----------------
__global__ __launch_bounds__(256) void k_fillP2(const int* __restrict__ src,
                                                const int* __restrict__ dst,
                                                const int* __restrict__ cntBB,
                                                const int* __restrict__ bbpartial,
                                                u32* __restrict__ stage) {
    __shared__ int lcur[NBK];
    const int t = threadIdx.x, c = blockIdx.x;
    for (int b = t; b < NBK; b += 256) {
        int i = b * NCH + c;
        lcur[b] = cntBB[i] + bbpartial[i >> 8];
    }
    __syncthreads();
    const int base = c * CHUNK;
    const int endE = min(base + CHUNK, NE);
    for (int e = base + t; e < endE; e += 256) {
        int s = src[e], d = dst[e];
        int slot = atomicAdd(&lcur[d >> 8], 1);
        stage[slot] = ((u32)(d & 255) << 16) | (u32)s;
    }
}

// ---------------- pass B: per-bucket LDS counting sort -> rowptr, dinv, csr16 ----------------
__global__ __launch_bounds__(256) void k_fillB(const u32* __restrict__ stage,
                                               const int* __restrict__ cntBB,
                                               const int* __restrict__ bbpartial,
                                               int* __restrict__ rowptr,
                                               float* __restrict__ dinv,
                                               ushort* __restrict__ csr16) {
    __shared__ int cnt[256];
    __shared__ int sm[256];
    __shared__ int cur[256];
    const int b = blockIdx.x, t = threadIdx.x;
    cnt[t] = 0;
    const int i0 = b * NCH;
    const int beg = cntBB[i0] + bbpartial[i0 >> 8];
    const int end = (b + 1 < NBK) ? cntBB[i0 + NCH] + bbpartial[(i0 + NCH) >> 8] : NE;
    __syncthreads();
    for (int i = beg + t; i < end; i += 256) atomicAdd(&cnt[(stage[i] >> 16) & 255u], 1);
    __syncthreads();
    const int v = cnt[t];
    sm[t] = v;
    __syncthreads();
    blockScan(sm);
    const int excl = sm[t] - v;
    const int n = b * 256 + t;
    if (n < NN) {
        rowptr[n] = beg + excl;
        dinv[n] = rsqrtf((float)(v + 1));  // +1 self-loop
    }
    if (b == NBK - 1 && t == 0) rowptr[NN] = NE;
    cur[t] = beg + excl;
    __syncthreads();
    for (int i = beg + t; i < end; i += 256) {
        u32 e = stage[i];
        int slot = atomicAdd(&cur[(e >> 16) & 255u], 1);
        csr16[slot] = (ushort)(e & 0xffffu);
    }
}

// ---------------- gather aggregation (zero LDS, high occupancy): u16 csr, w from dinv ----------------
template <int D, bool BIAS_RELU>
__global__ __launch_bounds__(256) void k_agge(const ushort* __restrict__ hb,
                                              const ushort* __restrict__ csr16,
                                              const int* __restrict__ rowptr,
                                              const float* __restrict__ dinv,
                                              const float* __restrict__ bias,
                                              u32* __restrict__ out) {
    constexpr int SUB = D / 8;        // lanes per node (8 for D=64, 16 for D=128)
    constexpr int NPB = 256 / SUB;    // nodes per block
    const int sub = threadIdx.x / SUB;
    const int sl = threadIdx.x % SUB;
    const int node = blockIdx.x * NPB + sub;
    if (node >= NN) return;

    const float dn = dinv[node];
    float acc[8];
    {
        uint4 v = *reinterpret_cast<const uint4*>(hb + (size_t)node * D + sl * 8);
        float w = dn * dn;
        acc[0] = w * blo(v.x); acc[1] = w * bhi(v.x);
        acc[2] = w * blo(v.y); acc[3] = w * bhi(v.y);
        acc[4] = w * blo(v.z); acc[5] = w * bhi(v.z);
        acc[6] = w * blo(v.w); acc[7] = w * bhi(v.w);
    }
    int j = rowptr[node];
    const int end = rowptr[node + 1];
    while ((j & 3) && j < end) {
        int s = csr16[j];
        uint4 g = *reinterpret_cast<const uint4*>(hb + (size_t)s * D + sl * 8);
        fma8(dn * dinv[s], g, acc);
        ++j;
    }
    for (; j + 4 <= end; j += 4) {
        ushort4 q = *reinterpret_cast<const ushort4*>(csr16 + j);
        uint4 g0 = *reinterpret_cast<const uint4*>(hb + (size_t)q.x * D + sl * 8);
        uint4 g1 = *reinterpret_cast<const uint4*>(hb + (size_t)q.y * D + sl * 8);
        uint4 g2 = *reinterpret_cast<const uint4*>(hb + (size_t)q.z * D + sl * 8);
        uint4 g3 = *reinterpret_cast<const uint4*>(hb + (size_t)q.w * D + sl * 8);
        float w0 = dn * dinv[q.x], w1 = dn * dinv[q.y];
        float w2 = dn * dinv[q.z], w3 = dn * dinv[q.w];
        fma8(w0, g0, acc);
        fma8(w1, g1, acc);
        fma8(w2, g2, acc);
        fma8(w3, g3, acc);
    }
    while (j < end) {
        int s = csr16[j];
        uint4 g = *reinterpret_cast<const uint4*>(hb + (size_t)s * D + sl * 8);
        fma8(dn * dinv[s], g, acc);
        ++j;
    }
    if (BIAS_RELU) {
        float4 b0 = *reinterpret_cast<const float4*>(bias + sl * 8);
        float4 b1v = *reinterpret_cast<const float4*>(bias + sl * 8 + 4);
        acc[0] = fmaxf(acc[0] + b0.x, 0.f); acc[1] = fmaxf(acc[1] + b0.y, 0.f);
        acc[2] = fmaxf(acc[2] + b0.z, 0.f); acc[3] = fmaxf(acc[3] + b0.w, 0.f);
        acc[4] = fmaxf(acc[4] + b1v.x, 0.f); acc[5] = fmaxf(acc[5] + b1v.y, 0.f);
        acc[6] = fmaxf(acc[6] + b1v.z, 0.f); acc[7] = fmaxf(acc[7] + b1v.w, 0.f);
    }
    uint4 o;
    o.x = f2b(acc[0]) | (f2b(acc[1]) << 16);
    o.y = f2b(acc[2]) | (f2b(acc[3]) << 16);
    o.z = f2b(acc[4]) | (f2b(acc[5]) << 16);
    o.w = f2b(acc[6]) | (f2b(acc[7]) << 16);
    *reinterpret_cast<uint4*>(reinterpret_cast<ushort*>(out) + (size_t)node * D + sl * 8) = o;
}

// ---------------- FUSED double GEMM, 32-row tiles (2x grid -> 2x occupancy), direct-global W ----------------
// agg1b bf16 -> GEMM1(W1)+b1+relu -> (h1 bf16 in LDS union) -> GEMM2(W2) -> tb bf16
__device__ inline float4 fmaf4(float s, float4 w, float4 a) {
    a.x = fmaf(s, w.x, a.x); a.y = fmaf(s, w.y, a.y);
    a.z = fmaf(s, w.z, a.z); a.w = fmaf(s, w.w, a.w);
    return a;
}

constexpr int GR = 32;  // rows per gemm12 block

__global__ __launch_bounds__(256) void k_gemm12(const ushort* __restrict__ A,
                                                const float* __restrict__ W1,
                                                const float* __restrict__ b1,
                                                const float* __restrict__ W2,
                                                u32* __restrict__ T) {
    constexpr int ASTR = 72;          // sA bf16 row stride (ushorts)
    __shared__ ushort sU16[GR * DH];  // 8 KB union: sA bf16 [32][72] then sH bf16 [32][128]
    const int t = threadIdx.x;
    const int row0 = blockIdx.x * GR;
    const int cg = t & 31;   // col group: cols cg*4..+3
    const int rw = t >> 5;   // row group: rows rw*4..+3 (8 groups x 4 rows)

    // ---- stage A (bf16, straight copy): 32 rows x 64 cols; one uint4 per thread
    {
        const int row = t >> 3;      // 0..31
        const int q = t & 7;         // 8-ushort chunk
        int gr = row0 + row;
        uint4 v = make_uint4(0u, 0u, 0u, 0u);
        if (gr < NN)
            v = *reinterpret_cast<const uint4*>(A + (size_t)gr * DI + q * 8);
        *reinterpret_cast<uint4*>(&sU16[row * ASTR + q * 8]) = v;
    }
    __syncthreads();

    // ---- GEMM1: K=64, W1 direct (cache-resident), +b1, relu -> h1 in registers
    const float* W1c = W1 + cg * 4;
    float4 acc[4];
#pragma unroll
    for (int j = 0; j < 4; ++j) acc[j] = make_float4(0.f, 0.f, 0.f, 0.f);

#pragma unroll 4
    for (int kk = 0; kk < DI; kk += 4) {
        float4 w0 = *reinterpret_cast<const float4*>(W1c + (kk + 0) * DH);
        float4 w1 = *reinterpret_cast<const float4*>(W1c + (kk + 1) * DH);
        float4 w2 = *reinterpret_cast<const float4*>(W1c + (kk + 2) * DH);
        float4 w3 = *reinterpret_cast<const float4*>(W1c + (kk + 3) * DH);
#pragma unroll
        for (int j = 0; j < 4; ++j) {
            uint2 av = *reinterpret_cast<const uint2*>(&sU16[(rw * 4 + j) * ASTR + kk]);
            acc[j] = fmaf4(blo(av.x), w0, acc[j]);
            acc[j] = fmaf4(bhi(av.x), w1, acc[j]);
            acc[j] = fmaf4(blo(av.y), w2, acc[j]);
            acc[j] = fmaf4(bhi(av.y), w3, acc[j]);
        }
    }
    {
        float4 bb = *reinterpret_cast<const float4*>(b1 + cg * 4);
#pragma unroll
        for (int j = 0; j < 4; ++j) {
            acc[j].x = fmaxf(acc[j].x + bb.x, 0.f);
            acc[j].y = fmaxf(acc[j].y + bb.y, 0.f);
            acc[j].z = fmaxf(acc[j].z + bb.z, 0.f);
            acc[j].w = fmaxf(acc[j].w + bb.w, 0.f);
        }
    }

    // ---- h1 (bf16) -> sH (same union; all sA reads complete first)
    __syncthreads();
#pragma unroll
    for (int j = 0; j < 4; ++j) {
        uint2 o = make_uint2(f2b(acc[j].x) | (f2b(acc[j].y) << 16),
                             f2b(acc[j].z) | (f2b(acc[j].w) << 16));
        *reinterpret_cast<uint2*>(&sU16[(rw * 4 + j) * DH + cg * 4]) = o;
    }
    __syncthreads();

    // ---- GEMM2: K=128, W2 direct -> tb bf16
    const float* W2c = W2 + cg * 4;
    float4 acc2[4];
#pragma unroll
    for (int j = 0; j < 4; ++j) acc2[j] = make_float4(0.f, 0.f, 0.f, 0.f);

#pragma unroll 4
    for (int kk = 0; kk < DH; kk += 4) {
        float4 w0 = *reinterpret_cast<const float4*>(W2c + (kk + 0) * DH);
        float4 w1 = *reinterpret_cast<const float4*>(W2c + (kk + 1) * DH);
        float4 w2 = *reinterpret_cast<const float4*>(W2c + (kk + 2) * DH);
        float4 w3 = *reinterpret_cast<const float4*>(W2c + (kk + 3) * DH);
#pragma unroll
        for (int j = 0; j < 4; ++j) {
            uint2 av = *reinterpret_cast<const uint2*>(&sU16[(rw * 4 + j) * DH + kk]);
            acc2[j] = fmaf4(blo(av.x), w0, acc2[j]);
            acc2[j] = fmaf4(bhi(av.x), w1, acc2[j]);
            acc2[j] = fmaf4(blo(av.y), w2, acc2[j]);
            acc2[j] = fmaf4(bhi(av.y), w3, acc2[j]);
        }
    }
#pragma unroll
    for (int j = 0; j < 4; ++j) {
        int gr = row0 + rw * 4 + j;
        if (gr < NN) {
            uint2 o = make_uint2(f2b(acc2[j].x) | (f2b(acc2[j].y) << 16),
                                 f2b(acc2[j].z) | (f2b(acc2[j].w) << 16));
            *reinterpret_cast<uint2*>(&T[(size_t)gr * (DH / 2) + cg * 2]) = o;
        }
    }
}

// ---------------- pooling (bf16 input, coalesced u32 reads) ----------------
constexpr int POOL_CHUNK = 64;
__global__ __launch_bounds__(256) void k_pool3(const u32* __restrict__ h2b,
                                               const int* __restrict__ batch,
                                               float* __restrict__ pooled) {
    const int c2 = threadIdx.x & 63;
    const int q = threadIdx.x >> 6;
    const int n0 = blockIdx.x * POOL_CHUNK;
    const int nEnd = min(n0 + POOL_CHUNK, NN);
    float a0 = 0.f, a1 = 0.f;
    int gcur = -1;
    for (int n = n0 + q; n < nEnd; n += 4) {
        int g = batch[n];
        if (g != gcur) {
            if (gcur >= 0) {
                atomicAdd(&pooled[gcur * DH + c2 * 2], a0);
                atomicAdd(&pooled[gcur * DH + c2 * 2 + 1], a1);
            }
            a0 = a1 = 0.f;
            gcur = g;
        }
        u32 v = h2b[(size_t)n * (DH / 2) + c2];
        a0 += blo(v);
        a1 += bhi(v);
    }
    if (gcur >= 0) {
        atomicAdd(&pooled[gcur * DH + c2 * 2], a0);
        atomicAdd(&pooled[gcur * DH + c2 * 2 + 1], a1);
    }
}

__global__ void k_head(const float* __restrict__ pooled, const int* __restrict__ gstart,
                       const float* __restrict__ Wf, const float* __restrict__ bf,
                       float* __restrict__ out) {
    int t = threadIdx.x;
    if (t >= NG * DO) return;
    int g = t / DO, o = t - g * DO;
    float acc = 0.0f;
    for (int k = 0; k < DH; ++k) acc += pooled[g * DH + k] * Wf[k * DO + o];
    float cnt = fmaxf((float)(gstart[g + 1] - gstart[g]), 1.0f);
    out[t] = acc / cnt + bf[o];
}

extern "C" void kernel_launch(void* const* d_in, const int* in_sizes, int n_in,
                              void* d_out, int out_size, void* d_ws, size_t ws_size,
                              hipStream_t stream) {
    const float* x   = (const float*)d_in[0];
    const int* ei    = (const int*)d_in[1];  // [2, NE] row-major
    const int* batch = (const int*)d_in[2];
    const float* W1  = (const float*)d_in[3];
    const float* b1  = (const float*)d_in[4];
    const float* W2  = (const float*)d_in[5];
    const float* b2  = (const float*)d_in[6];
    const float* Wf  = (const float*)d_in[7];
    const float* bf  = (const float*)d_in[8];
    float* out = (float*)d_out;

    const int* src = ei;
    const int* dst = ei + NE;

    // workspace (4B units; ~44 MB total)
    int* rowptr    = (int*)d_ws;               // 50056 (NN+1 used)
    int* bbpartial = rowptr + 50056;           // 256
    int* gstart    = bbpartial + 256;          // 80
    int* cntBB     = gstart + 80;              // 38416 ([b][c] bucket-major)
    ushort* csr16  = (ushort*)(cntBB + 38416); // NE u16 = 400000 u32
    float* dinv    = (float*)((u32*)(cntBB + 38416) + 400000);  // 50048
    u32* xbu       = (u32*)(dinv + 50048);     // 1.6M u32 (NN x 64 bf16)
    u32* stage     = xbu + 1600000;            // 0.8M u32 (NE packed entries)
    u32* agg1bu    = stage + 800000;           // 1.6M u32 (NN x 64 bf16)
    u32* tbu       = agg1bu + 1600000;         // 3.2M u32 (NN x 128 bf16)
    u32* h2b       = tbu + 3200000;            // 3.2M u32 (NN x 128 bf16)
    float* pooled  = (float*)(h2b + 3200000);  // 8192

    ushort* xb    = (ushort*)xbu;
    ushort* agg1b = (ushort*)agg1bu;
    ushort* tb    = (ushort*)tbu;

    const int B = 256;
    k_init<<<(NN * DI / 8 + B - 1) / B, B, 0, stream>>>(x, (uint4*)xb, pooled, batch, gstart);
    k_histc<<<NCH, 256, 0, stream>>>(dst, cntBB);
    k_scanBB1<<<NBB, SCAN_B, 0, stream>>>(cntBB, bbpartial);
    k_scanB<<<1, SCAN_B, 0, stream>>>(bbpartial);
    k_fillP2<<<NCH, 256, 0, stream>>>(src, dst, cntBB, bbpartial, stage);
    k_fillB<<<NBK, 256, 0, stream>>>(stage, cntBB, bbpartial, rowptr, dinv, csr16);

    // layer 1 agg (zero-LDS, high occupancy): gather xb -> agg1b bf16
    k_agge<DI, false><<<(NN + 31) / 32, 256, 0, stream>>>(xb, csr16, rowptr, dinv,
                                                          nullptr, agg1bu);
    // fused GEMM1+GEMM2 (32-row tiles, direct-global W): agg1b -> h1 (LDS) -> tb
    k_gemm12<<<(NN + GR - 1) / GR, 256, 0, stream>>>(agg1b, W1, b1, W2, tbu);

    // layer-2 agg: gather tb, +b2, relu -> h2b (bf16)
    k_agge<DH, true><<<(NN + 15) / 16, 256, 0, stream>>>(tb, csr16, rowptr, dinv, b2, h2b);

    // pool + head
    k_pool3<<<(NN + POOL_CHUNK - 1) / POOL_CHUNK, 256, 0, stream>>>(h2b, batch, pooled);
    k_head<<<1, 256, 0, stream>>>(pooled, gstart, Wf, bf, out);
}

// Round 22
// 150.199 us; speedup vs baseline: 1.1448x; 1.1415x over previous
//
#include <hip/hip_runtime.h>

constexpr int NN = 50000;   // nodes
constexpr int NE = 800000;  // edges
constexpr int NG = 64;      // graphs
constexpr int DI = 64;      // in dim
constexpr int DH = 128;     // hidden dim
constexpr int DO = 3;       // out dim

constexpr int SCAN_B = 256;
constexpr int NBK = 196;                  // dst buckets of 256 nodes (dst >> 8)
constexpr int CHUNK = 4096;               // edges per partition block
constexpr int NCH = (NE + CHUNK - 1) / CHUNK;  // 196 chunks
constexpr int BBTOT = NBK * NCH;          // 38416 (bucket-major [b][c])
constexpr int NBB = (BBTOT + 255) / 256;  // 151 scan blocks

typedef unsigned int u32;
typedef __attribute__((ext_vector_type(8))) short bf16x8;
typedef __attribute__((ext_vector_type(4))) float f32x4;

// ---------------- bf16 helpers ----------------
__device__ inline float blo(u32 u) { return __uint_as_float(u << 16); }
__device__ inline float bhi(u32 u) { return __uint_as_float(u & 0xffff0000u); }
__device__ inline u32 f2b(float f) {  // RNE round to bf16 (16-bit pattern)
    u32 u = __float_as_uint(f);
    return (u + 0x7fffu + ((u >> 16) & 1u)) >> 16;
}
__device__ inline void fma8(float w, uint4 v, float acc[8]) {
    acc[0] = fmaf(w, blo(v.x), acc[0]); acc[1] = fmaf(w, bhi(v.x), acc[1]);
    acc[2] = fmaf(w, blo(v.y), acc[2]); acc[3] = fmaf(w, bhi(v.y), acc[3]);
    acc[4] = fmaf(w, blo(v.z), acc[4]); acc[5] = fmaf(w, bhi(v.z), acc[5]);
    acc[6] = fmaf(w, blo(v.w), acc[6]); acc[7] = fmaf(w, bhi(v.w), acc[7]);
}

// ---------------- fused: x->bf16, W->bf16 transposed, zero pooled, gstart ----------------
__global__ void k_init(const float* __restrict__ x, uint4* __restrict__ xb,
                       float* __restrict__ pooled, const int* __restrict__ batch,
                       int* __restrict__ gstart, const float* __restrict__ W1,
                       const float* __restrict__ W2, ushort* __restrict__ w1bt,
                       ushort* __restrict__ w2bt) {
    int i = blockIdx.x * blockDim.x + threadIdx.x;
    if (i < NN * DI / 8) {
        float4 a = reinterpret_cast<const float4*>(x)[i * 2];
        float4 b = reinterpret_cast<const float4*>(x)[i * 2 + 1];
        uint4 o;
        o.x = f2b(a.x) | (f2b(a.y) << 16);
        o.y = f2b(a.z) | (f2b(a.w) << 16);
        o.z = f2b(b.x) | (f2b(b.y) << 16);
        o.w = f2b(b.z) | (f2b(b.w) << 16);
        xb[i] = o;
    }
    if (i < NG * DH) pooled[i] = 0.0f;
    if (i < DH * DI) w1bt[i] = (ushort)f2b(W1[(i & (DI - 1)) * DH + (i >> 6)]);       // [c][k]
    if (i < DH * DH) w2bt[i] = (ushort)f2b(W2[(i & (DH - 1)) * DH + (i >> 7)]);       // [c][k]
    if (blockIdx.x == 0 && threadIdx.x <= NG) {
        int g = threadIdx.x;
        int lo = 0, hi = NN;
        while (lo < hi) {
            int mid = (lo + hi) >> 1;
            if (batch[mid] < g) lo = mid + 1; else hi = mid;
        }
        gstart[g] = lo;
    }
}

// ---------------- hist: per-(bucket,chunk) LDS counts ONLY (no global atomics) ----------------
__global__ __launch_bounds__(256) void k_histc(const int* __restrict__ dst,
                                               int* __restrict__ cntBB) {
    __shared__ int lcnt[NBK];
    const int t = threadIdx.x, c = blockIdx.x;
    for (int b = t; b < NBK; b += 256) lcnt[b] = 0;
    __syncthreads();
    const int base = c * CHUNK;
    const int endE = min(base + CHUNK, NE);
    for (int e = base + t; e < endE; e += 256) atomicAdd(&lcnt[dst[e] >> 8], 1);
    __syncthreads();
    for (int b = t; b < NBK; b += 256) cntBB[b * NCH + c] = lcnt[b];
}

// block-local inclusive scan helper over sm[256]
__device__ inline void blockScan(int* sm) {
    for (int off = 1; off < SCAN_B; off <<= 1) {
        int add = (threadIdx.x >= off) ? sm[threadIdx.x - off] : 0;
        __syncthreads();
        sm[threadIdx.x] += add;
        __syncthreads();
    }
}

// ---------------- cntBB block scans (in place) + per-block sums ----------------
__global__ void k_scanBB1(int* __restrict__ cntBB, int* __restrict__ bbpartial) {
    __shared__ int sm[SCAN_B];
    int i = blockIdx.x * SCAN_B + threadIdx.x;
    int v = (i < BBTOT) ? cntBB[i] : 0;
    sm[threadIdx.x] = v;
    __syncthreads();
    blockScan(sm);
    if (i < BBTOT) cntBB[i] = sm[threadIdx.x] - v;  // block-local exclusive
    if (threadIdx.x == SCAN_B - 1) bbpartial[blockIdx.x] = sm[SCAN_B - 1];
}

__global__ void k_scanB(int* __restrict__ bbpartial) {  // single block, NBB<=256
    __shared__ int sm[SCAN_B];
    int v = (threadIdx.x < NBB) ? bbpartial[threadIdx.x] : 0;
    sm[threadIdx.x] = v;
    __syncthreads();
    blockScan(sm);
    if (threadIdx.x < NBB) bbpartial[threadIdx.x] = sm[threadIdx.x] - v;  // exclusive
}

// ---------------- pass 2: bin (src | dst&255) into bucket-sorted stage via LDS cursors ----------------
__global__ __launch_bounds__(256) void k_fillP2(const int* __restrict__ src,
                                                const int* __restrict__ dst,
                                                const int* __restrict__ cntBB,
                                                const int* __restrict__ bbpartial,
                                                u32* __restrict__ stage) {
    __shared__ int lcur[NBK];
    const int t = threadIdx.x, c = blockIdx.x;
    for (int b = t; b < NBK; b += 256) {
        int i = b * NCH + c;
        lcur[b] = cntBB[i] + bbpartial[i >> 8];
    }
    __syncthreads();
    const int base = c * CHUNK;
    const int endE = min(base + CHUNK, NE);
    for (int e = base + t; e < endE; e += 256) {
        int s = src[e], d = dst[e];
        int slot = atomicAdd(&lcur[d >> 8], 1);
        stage[slot] = ((u32)(d & 255) << 16) | (u32)s;
    }
}

// ---------------- pass B: per-bucket LDS counting sort -> rowptr, dinv, csr16 ----------------
__global__ __launch_bounds__(256) void k_fillB(const u32* __restrict__ stage,
                                               const int* __restrict__ cntBB,
                                               const int* __restrict__ bbpartial,
                                               int* __restrict__ rowptr,
                                               float* __restrict__ dinv,
                                               ushort* __restrict__ csr16) {
    __shared__ int cnt[256];
    __shared__ int sm[256];
    __shared__ int cur[256];
    const int b = blockIdx.x, t = threadIdx.x;
    cnt[t] = 0;
    const int i0 = b * NCH;
    const int beg = cntBB[i0] + bbpartial[i0 >> 8];
    const int end = (b + 1 < NBK) ? cntBB[i0 + NCH] + bbpartial[(i0 + NCH) >> 8] : NE;
    __syncthreads();
    for (int i = beg + t; i < end; i += 256) atomicAdd(&cnt[(stage[i] >> 16) & 255u], 1);
    __syncthreads();
    const int v = cnt[t];
    sm[t] = v;
    __syncthreads();
    blockScan(sm);
    const int excl = sm[t] - v;
    const int n = b * 256 + t;
    if (n < NN) {
        rowptr[n] = beg + excl;
        dinv[n] = rsqrtf((float)(v + 1));  // +1 self-loop
    }
    if (b == NBK - 1 && t == 0) rowptr[NN] = NE;
    cur[t] = beg + excl;
    __syncthreads();
    for (int i = beg + t; i < end; i += 256) {
        u32 e = stage[i];
        int slot = atomicAdd(&cur[(e >> 16) & 255u], 1);
        csr16[slot] = (ushort)(e & 0xffffu);
    }
}

// ---------------- gather aggregation (zero LDS, high occupancy): u16 csr, w from dinv ----------------
template <int D, bool BIAS_RELU>
__global__ __launch_bounds__(256) void k_agge(const ushort* __restrict__ hb,
                                              const ushort* __restrict__ csr16,
                                              const int* __restrict__ rowptr,
                                              const float* __restrict__ dinv,
                                              const float* __restrict__ bias,
                                              u32* __restrict__ out) {
    constexpr int SUB = D / 8;        // lanes per node (8 for D=64, 16 for D=128)
    constexpr int NPB = 256 / SUB;    // nodes per block
    const int sub = threadIdx.x / SUB;
    const int sl = threadIdx.x % SUB;
    const int node = blockIdx.x * NPB + sub;
    if (node >= NN) return;

    const float dn = dinv[node];
    float acc[8];
    {
        uint4 v = *reinterpret_cast<const uint4*>(hb + (size_t)node * D + sl * 8);
        float w = dn * dn;
        acc[0] = w * blo(v.x); acc[1] = w * bhi(v.x);
        acc[2] = w * blo(v.y); acc[3] = w * bhi(v.y);
        acc[4] = w * blo(v.z); acc[5] = w * bhi(v.z);
        acc[6] = w * blo(v.w); acc[7] = w * bhi(v.w);
    }
    int j = rowptr[node];
    const int end = rowptr[node + 1];
    while ((j & 3) && j < end) {
        int s = csr16[j];
        uint4 g = *reinterpret_cast<const uint4*>(hb + (size_t)s * D + sl * 8);
        fma8(dn * dinv[s], g, acc);
        ++j;
    }
    for (; j + 4 <= end; j += 4) {
        ushort4 q = *reinterpret_cast<const ushort4*>(csr16 + j);
        uint4 g0 = *reinterpret_cast<const uint4*>(hb + (size_t)q.x * D + sl * 8);
        uint4 g1 = *reinterpret_cast<const uint4*>(hb + (size_t)q.y * D + sl * 8);
        uint4 g2 = *reinterpret_cast<const uint4*>(hb + (size_t)q.z * D + sl * 8);
        uint4 g3 = *reinterpret_cast<const uint4*>(hb + (size_t)q.w * D + sl * 8);
        float w0 = dn * dinv[q.x], w1 = dn * dinv[q.y];
        float w2 = dn * dinv[q.z], w3 = dn * dinv[q.w];
        fma8(w0, g0, acc);
        fma8(w1, g1, acc);
        fma8(w2, g2, acc);
        fma8(w3, g3, acc);
    }
    while (j < end) {
        int s = csr16[j];
        uint4 g = *reinterpret_cast<const uint4*>(hb + (size_t)s * D + sl * 8);
        fma8(dn * dinv[s], g, acc);
        ++j;
    }
    if (BIAS_RELU) {
        float4 b0 = *reinterpret_cast<const float4*>(bias + sl * 8);
        float4 b1v = *reinterpret_cast<const float4*>(bias + sl * 8 + 4);
        acc[0] = fmaxf(acc[0] + b0.x, 0.f); acc[1] = fmaxf(acc[1] + b0.y, 0.f);
        acc[2] = fmaxf(acc[2] + b0.z, 0.f); acc[3] = fmaxf(acc[3] + b0.w, 0.f);
        acc[4] = fmaxf(acc[4] + b1v.x, 0.f); acc[5] = fmaxf(acc[5] + b1v.y, 0.f);
        acc[6] = fmaxf(acc[6] + b1v.z, 0.f); acc[7] = fmaxf(acc[7] + b1v.w, 0.f);
    }
    uint4 o;
    o.x = f2b(acc[0]) | (f2b(acc[1]) << 16);
    o.y = f2b(acc[2]) | (f2b(acc[3]) << 16);
    o.z = f2b(acc[4]) | (f2b(acc[5]) << 16);
    o.w = f2b(acc[6]) | (f2b(acc[7]) << 16);
    *reinterpret_cast<uint4*>(reinterpret_cast<ushort*>(out) + (size_t)node * D + sl * 8) = o;
}

// ---------------- MFMA fused double GEMM ----------------
// agg1b bf16 -> MFMA GEMM1 (W1bt) +b1+relu -> sH (LDS bf16, per-wave) -> MFMA GEMM2 (W2bt) -> tb bf16
// Fragment maps: A/B: 16-dim = lane&15, k = kt*32 + (lane>>4)*8 + j (consistent on both operands
// -> any common k-permutation cancels). C/D (HW-verified): col = lane&15, row = (lane>>4)*4 + reg.
__global__ __launch_bounds__(256) void k_gemm12m(const ushort* __restrict__ A,
                                                 const ushort* __restrict__ w1bt,
                                                 const float* __restrict__ b1,
                                                 const ushort* __restrict__ w2bt,
                                                 ushort* __restrict__ T) {
    constexpr int HP = 136;             // sH row stride (ushorts), pad kills bank conflicts
    __shared__ ushort sH[4 * 16 * HP];  // 17408 B
    const int t = threadIdx.x;
    const int w = t >> 6;        // wave 0..3
    const int l = t & 63;        // lane
    const int r16 = l & 15;      // fragment 16-dim index
    const int kg = l >> 4;       // k-group 0..3
    const int row0 = blockIdx.x * 64 + w * 16;
    ushort* sHw = &sH[w * 16 * HP];

    // ---- A fragments for GEMM1 (rows from agg1b, clamped for tail block)
    bf16x8 a1_0, a1_1;
    {
        int gr = row0 + r16;
        const ushort* Ap = A + (size_t)(gr < NN ? gr : NN - 1) * DI + kg * 8;
        a1_0 = *reinterpret_cast<const bf16x8*>(Ap);
        a1_1 = *reinterpret_cast<const bf16x8*>(Ap + 32);
    }

    // ---- GEMM1: 8 col-tiles of 16, K=64 (2 MFMA each), +b1, relu -> sH
#pragma unroll
    for (int ct = 0; ct < 8; ++ct) {
        const ushort* Bp = w1bt + (size_t)(ct * 16 + r16) * DI + kg * 8;
        bf16x8 b0 = *reinterpret_cast<const bf16x8*>(Bp);
        bf16x8 bq = *reinterpret_cast<const bf16x8*>(Bp + 32);
        f32x4 c = {0.f, 0.f, 0.f, 0.f};
        c = __builtin_amdgcn_mfma_f32_16x16x32_bf16(a1_0, b0, c, 0, 0, 0);
        c = __builtin_amdgcn_mfma_f32_16x16x32_bf16(a1_1, bq, c, 0, 0, 0);
        float bb = b1[ct * 16 + r16];
#pragma unroll
        for (int r = 0; r < 4; ++r) {
            float v = fmaxf(c[r] + bb, 0.f);
            sHw[(kg * 4 + r) * HP + ct * 16 + r16] = (ushort)f2b(v);
        }
    }
    __syncthreads();

    // ---- A fragments for GEMM2 from sH (conflict-free b128 via pad-136)
    bf16x8 a2_0 = *reinterpret_cast<const bf16x8*>(&sHw[r16 * HP + 0 * 32 + kg * 8]);
    bf16x8 a2_1 = *reinterpret_cast<const bf16x8*>(&sHw[r16 * HP + 1 * 32 + kg * 8]);
    bf16x8 a2_2 = *reinterpret_cast<const bf16x8*>(&sHw[r16 * HP + 2 * 32 + kg * 8]);
    bf16x8 a2_3 = *reinterpret_cast<const bf16x8*>(&sHw[r16 * HP + 3 * 32 + kg * 8]);

    // ---- GEMM2: 8 col-tiles, K=128 (4 MFMA each) -> tb bf16
#pragma unroll
    for (int ct = 0; ct < 8; ++ct) {
        const ushort* Bp = w2bt + (size_t)(ct * 16 + r16) * DH + kg * 8;
        bf16x8 b0 = *reinterpret_cast<const bf16x8*>(Bp);
        bf16x8 b1v = *reinterpret_cast<const bf16x8*>(Bp + 32);
        bf16x8 b2v = *reinterpret_cast<const bf16x8*>(Bp + 64);
        bf16x8 b3v = *reinterpret_cast<const bf16x8*>(Bp + 96);
        f32x4 c = {0.f, 0.f, 0.f, 0.f};
        c = __builtin_amdgcn_mfma_f32_16x16x32_bf16(a2_0, b0, c, 0, 0, 0);
        c = __builtin_amdgcn_mfma_f32_16x16x32_bf16(a2_1, b1v, c, 0, 0, 0);
        c = __builtin_amdgcn_mfma_f32_16x16x32_bf16(a2_2, b2v, c, 0, 0, 0);
        c = __builtin_amdgcn_mfma_f32_16x16x32_bf16(a2_3, b3v, c, 0, 0, 0);
#pragma unroll
        for (int r = 0; r < 4; ++r) {
            int gr = row0 + kg * 4 + r;
            if (gr < NN)
                T[(size_t)gr * DH + ct * 16 + r16] = (ushort)f2b(c[r]);
        }
    }
}

// ---------------- pooling (bf16 input, coalesced u32 reads) ----------------
constexpr int POOL_CHUNK = 64;
__global__ __launch_bounds__(256) void k_pool3(const u32* __restrict__ h2b,
                                               const int* __restrict__ batch,
                                               float* __restrict__ pooled) {
    const int c2 = threadIdx.x & 63;
    const int q = threadIdx.x >> 6;
    const int n0 = blockIdx.x * POOL_CHUNK;
    const int nEnd = min(n0 + POOL_CHUNK, NN);
    float a0 = 0.f, a1 = 0.f;
    int gcur = -1;
    for (int n = n0 + q; n < nEnd; n += 4) {
        int g = batch[n];
        if (g != gcur) {
            if (gcur >= 0) {
                atomicAdd(&pooled[gcur * DH + c2 * 2], a0);
                atomicAdd(&pooled[gcur * DH + c2 * 2 + 1], a1);
            }
            a0 = a1 = 0.f;
            gcur = g;
        }
        u32 v = h2b[(size_t)n * (DH / 2) + c2];
        a0 += blo(v);
        a1 += bhi(v);
    }
    if (gcur >= 0) {
        atomicAdd(&pooled[gcur * DH + c2 * 2], a0);
        atomicAdd(&pooled[gcur * DH + c2 * 2 + 1], a1);
    }
}

__global__ void k_head(const float* __restrict__ pooled, const int* __restrict__ gstart,
                       const float* __restrict__ Wf, const float* __restrict__ bf,
                       float* __restrict__ out) {
    int t = threadIdx.x;
    if (t >= NG * DO) return;
    int g = t / DO, o = t - g * DO;
    float acc = 0.0f;
    for (int k = 0; k < DH; ++k) acc += pooled[g * DH + k] * Wf[k * DO + o];
    float cnt = fmaxf((float)(gstart[g + 1] - gstart[g]), 1.0f);
    out[t] = acc / cnt + bf[o];
}

extern "C" void kernel_launch(void* const* d_in, const int* in_sizes, int n_in,
                              void* d_out, int out_size, void* d_ws, size_t ws_size,
                              hipStream_t stream) {
    const float* x   = (const float*)d_in[0];
    const int* ei    = (const int*)d_in[1];  // [2, NE] row-major
    const int* batch = (const int*)d_in[2];
    const float* W1  = (const float*)d_in[3];
    const float* b1  = (const float*)d_in[4];
    const float* W2  = (const float*)d_in[5];
    const float* b2  = (const float*)d_in[6];
    const float* Wf  = (const float*)d_in[7];
    const float* bf  = (const float*)d_in[8];
    float* out = (float*)d_out;

    const int* src = ei;
    const int* dst = ei + NE;

    // workspace (4B units; ~44 MB total)
    int* rowptr    = (int*)d_ws;               // 50056 (NN+1 used)
    int* bbpartial = rowptr + 50056;           // 256
    int* gstart    = bbpartial + 256;          // 80
    int* cntBB     = gstart + 80;              // 38416 ([b][c] bucket-major)
    ushort* csr16  = (ushort*)(cntBB + 38416); // NE u16 = 400000 u32
    float* dinv    = (float*)((u32*)(cntBB + 38416) + 400000);  // 50048
    u32* xbu       = (u32*)(dinv + 50048);     // 1.6M u32 (NN x 64 bf16)
    u32* stage     = xbu + 1600000;            // 0.8M u32 (NE packed entries)
    u32* agg1bu    = stage + 800000;           // 1.6M u32 (NN x 64 bf16)
    u32* tbu       = agg1bu + 1600000;         // 3.2M u32 (NN x 128 bf16)
    u32* h2b       = tbu + 3200000;            // 3.2M u32 (NN x 128 bf16)
    float* pooled  = (float*)(h2b + 3200000);  // 8192
    ushort* w1bt   = (ushort*)(pooled + 8192); // 8192 ushort (W1^T bf16 [128][64])
    ushort* w2bt   = w1bt + 8192;              // 16384 ushort (W2^T bf16 [128][128])

    ushort* xb    = (ushort*)xbu;
    ushort* agg1b = (ushort*)agg1bu;
    ushort* tb    = (ushort*)tbu;

    const int B = 256;
    k_init<<<(NN * DI / 8 + B - 1) / B, B, 0, stream>>>(x, (uint4*)xb, pooled, batch,
                                                        gstart, W1, W2, w1bt, w2bt);
    k_histc<<<NCH, 256, 0, stream>>>(dst, cntBB);
    k_scanBB1<<<NBB, SCAN_B, 0, stream>>>(cntBB, bbpartial);
    k_scanB<<<1, SCAN_B, 0, stream>>>(bbpartial);
    k_fillP2<<<NCH, 256, 0, stream>>>(src, dst, cntBB, bbpartial, stage);
    k_fillB<<<NBK, 256, 0, stream>>>(stage, cntBB, bbpartial, rowptr, dinv, csr16);

    // layer 1 agg (zero-LDS, high occupancy): gather xb -> agg1b bf16
    k_agge<DI, false><<<(NN + 31) / 32, 256, 0, stream>>>(xb, csr16, rowptr, dinv,
                                                          nullptr, agg1bu);
    // MFMA fused GEMM1+GEMM2: agg1b -> h1 (LDS bf16) -> tb
    k_gemm12m<<<(NN + 63) / 64, 256, 0, stream>>>(agg1b, w1bt, b1, w2bt, tb);

    // layer-2 agg: gather tb, +b2, relu -> h2b (bf16)
    k_agge<DH, true><<<(NN + 15) / 16, 256, 0, stream>>>(tb, csr16, rowptr, dinv, b2, h2b);

    // pool + head
    k_pool3<<<(NN + POOL_CHUNK - 1) / POOL_CHUNK, 256, 0, stream>>>(h2b, batch, pooled);
    k_head<<<1, 256, 0, stream>>>(pooled, gstart, Wf, bf, out);
}

// Round 23
// 148.419 us; speedup vs baseline: 1.1585x; 1.0120x over previous
//
#include <hip/hip_runtime.h>

constexpr int NN = 50000;   // nodes
constexpr int NE = 800000;  // edges
constexpr int NG = 64;      // graphs
constexpr int DI = 64;      // in dim
constexpr int DH = 128;     // hidden dim
constexpr int DO = 3;       // out dim

constexpr int SCAN_B = 256;
constexpr int NBK = 196;                  // dst buckets of 256 nodes (dst >> 8)
constexpr int CHUNK = 4096;               // edges per partition block
constexpr int NCH = (NE + CHUNK - 1) / CHUNK;  // 196 chunks
constexpr int BBTOT = NBK * NCH;          // 38416 (bucket-major [b][c])
constexpr int NBB = (BBTOT + 255) / 256;  // 151 scan blocks

typedef unsigned int u32;
typedef __attribute__((ext_vector_type(8))) short bf16x8;
typedef __attribute__((ext_vector_type(4))) float f32x4;

// ---------------- bf16 helpers ----------------
__device__ inline float blo(u32 u) { return __uint_as_float(u << 16); }
__device__ inline float bhi(u32 u) { return __uint_as_float(u & 0xffff0000u); }
__device__ inline u32 f2b(float f) {  // RNE round to bf16 (16-bit pattern)
    u32 u = __float_as_uint(f);
    return (u + 0x7fffu + ((u >> 16) & 1u)) >> 16;
}
__device__ inline void fma8(float w, uint4 v, float acc[8]) {
    acc[0] = fmaf(w, blo(v.x), acc[0]); acc[1] = fmaf(w, bhi(v.x), acc[1]);
    acc[2] = fmaf(w, blo(v.y), acc[2]); acc[3] = fmaf(w, bhi(v.y), acc[3]);
    acc[4] = fmaf(w, blo(v.z), acc[4]); acc[5] = fmaf(w, bhi(v.z), acc[5]);
    acc[6] = fmaf(w, blo(v.w), acc[6]); acc[7] = fmaf(w, bhi(v.w), acc[7]);
}

// block-local inclusive scan helper over sm[256]
__device__ inline void blockScan(int* sm) {
    for (int off = 1; off < SCAN_B; off <<= 1) {
        int add = (threadIdx.x >= off) ? sm[threadIdx.x - off] : 0;
        __syncthreads();
        sm[threadIdx.x] += add;
        __syncthreads();
    }
}

// ---------------- fused: x->bf16, W->bf16^T, zero pooled, gstart, AND histc (blocks<NCH) ----------------
__global__ __launch_bounds__(256) void k_init(const float* __restrict__ x,
                                              uint4* __restrict__ xb,
                                              float* __restrict__ pooled,
                                              const int* __restrict__ batch,
                                              int* __restrict__ gstart,
                                              const float* __restrict__ W1,
                                              const float* __restrict__ W2,
                                              ushort* __restrict__ w1bt,
                                              ushort* __restrict__ w2bt,
                                              const int* __restrict__ dst,
                                              int* __restrict__ cntBB) {
    __shared__ int lcnt[NBK];
    const int t = threadIdx.x;
    const int c = blockIdx.x;
    const bool doHist = (c < NCH);
    if (doHist) {
        for (int b = t; b < NBK; b += 256) lcnt[b] = 0;
        __syncthreads();
        const int base = c * CHUNK;
        const int endE = min(base + CHUNK, NE);
        for (int e = base + t; e < endE; e += 256) atomicAdd(&lcnt[dst[e] >> 8], 1);
    }

    int i = blockIdx.x * blockDim.x + t;
    if (i < NN * DI / 8) {
        float4 a = reinterpret_cast<const float4*>(x)[i * 2];
        float4 b = reinterpret_cast<const float4*>(x)[i * 2 + 1];
        uint4 o;
        o.x = f2b(a.x) | (f2b(a.y) << 16);
        o.y = f2b(a.z) | (f2b(a.w) << 16);
        o.z = f2b(b.x) | (f2b(b.y) << 16);
        o.w = f2b(b.z) | (f2b(b.w) << 16);
        xb[i] = o;
    }
    if (i < NG * DH) pooled[i] = 0.0f;
    if (i < DH * DI) w1bt[i] = (ushort)f2b(W1[(i & (DI - 1)) * DH + (i >> 6)]);  // [c][k]
    if (i < DH * DH) w2bt[i] = (ushort)f2b(W2[(i & (DH - 1)) * DH + (i >> 7)]);  // [c][k]
    if (blockIdx.x == 0 && t <= NG) {
        int g = t;
        int lo = 0, hi = NN;
        while (lo < hi) {
            int mid = (lo + hi) >> 1;
            if (batch[mid] < g) lo = mid + 1; else hi = mid;
        }
        gstart[g] = lo;
    }

    if (doHist) {
        __syncthreads();
        for (int b = t; b < NBK; b += 256) cntBB[b * NCH + c] = lcnt[b];
    }
}

// ---------------- cntBB block scans (in place) + per-block sums ----------------
__global__ void k_scanBB1(int* __restrict__ cntBB, int* __restrict__ bbpartial) {
    __shared__ int sm[SCAN_B];
    int i = blockIdx.x * SCAN_B + threadIdx.x;
    int v = (i < BBTOT) ? cntBB[i] : 0;
    sm[threadIdx.x] = v;
    __syncthreads();
    blockScan(sm);
    if (i < BBTOT) cntBB[i] = sm[threadIdx.x] - v;  // block-local exclusive
    if (threadIdx.x == SCAN_B - 1) bbpartial[blockIdx.x] = sm[SCAN_B - 1];
}

// ---------------- pass 2: bin (src | dst&255) into bucket-sorted stage; bbpartial scanned in LDS ----------------
__global__ __launch_bounds__(256) void k_fillP2(const int* __restrict__ src,
                                                const int* __restrict__ dst,
                                                const int* __restrict__ cntBB,
                                                const int* __restrict__ bbpartial,
                                                u32* __restrict__ stage) {
    __shared__ int lcur[NBK];
    __shared__ int sm[SCAN_B];
    __shared__ int sbbx[SCAN_B];
    const int t = threadIdx.x, c = blockIdx.x;
    // local exclusive scan of bbpartial (NBB=151 raw per-block sums)
    int vv = (t < NBB) ? bbpartial[t] : 0;
    sm[t] = vv;
    __syncthreads();
    blockScan(sm);
    sbbx[t] = sm[t] - vv;  // exclusive
    __syncthreads();
    for (int b = t; b < NBK; b += 256) {
        int i = b * NCH + c;
        lcur[b] = cntBB[i] + sbbx[i >> 8];
    }
    __syncthreads();
    const int base = c * CHUNK;
    const int endE = min(base + CHUNK, NE);
    for (int e = base + t; e < endE; e += 256) {
        int s = src[e], d = dst[e];
        int slot = atomicAdd(&lcur[d >> 8], 1);
        stage[slot] = ((u32)(d & 255) << 16) | (u32)s;
    }
}

// ---------------- pass B: per-bucket LDS counting sort -> rowptr, dinv, csr16 ----------------
__global__ __launch_bounds__(256) void k_fillB(const u32* __restrict__ stage,
                                               const int* __restrict__ cntBB,
                                               const int* __restrict__ bbpartial,
                                               int* __restrict__ rowptr,
                                               float* __restrict__ dinv,
                                               ushort* __restrict__ csr16) {
    __shared__ int cnt[256];
    __shared__ int sm[256];
    __shared__ int cur[256];
    __shared__ int sbbx[256];
    const int b = blockIdx.x, t = threadIdx.x;
    // local exclusive scan of bbpartial
    int vv = (t < NBB) ? bbpartial[t] : 0;
    sm[t] = vv;
    __syncthreads();
    blockScan(sm);
    sbbx[t] = sm[t] - vv;
    cnt[t] = 0;
    __syncthreads();
    const int i0 = b * NCH;
    const int beg = cntBB[i0] + sbbx[i0 >> 8];
    const int end = (b + 1 < NBK) ? cntBB[i0 + NCH] + sbbx[(i0 + NCH) >> 8] : NE;
    for (int i = beg + t; i < end; i += 256) atomicAdd(&cnt[(stage[i] >> 16) & 255u], 1);
    __syncthreads();
    const int v = cnt[t];
    sm[t] = v;
    __syncthreads();
    blockScan(sm);
    const int excl = sm[t] - v;
    const int n = b * 256 + t;
    if (n < NN) {
        rowptr[n] = beg + excl;
        dinv[n] = rsqrtf((float)(v + 1));  // +1 self-loop
    }
    if (b == NBK - 1 && t == 0) rowptr[NN] = NE;
    cur[t] = beg + excl;
    __syncthreads();
    for (int i = beg + t; i < end; i += 256) {
        u32 e = stage[i];
        int slot = atomicAdd(&cur[(e >> 16) & 255u], 1);
        csr16[slot] = (ushort)(e & 0xffffu);
    }
}

// ---------------- gather aggregation (zero LDS, high occupancy): u16 csr, w from dinv ----------------
template <int D, bool BIAS_RELU>
__global__ __launch_bounds__(256) void k_agge(const ushort* __restrict__ hb,
                                              const ushort* __restrict__ csr16,
                                              const int* __restrict__ rowptr,
                                              const float* __restrict__ dinv,
                                              const float* __restrict__ bias,
                                              u32* __restrict__ out) {
    constexpr int SUB = D / 8;        // lanes per node (8 for D=64, 16 for D=128)
    constexpr int NPB = 256 / SUB;    // nodes per block
    const int sub = threadIdx.x / SUB;
    const int sl = threadIdx.x % SUB;
    const int node = blockIdx.x * NPB + sub;
    if (node >= NN) return;

    const float dn = dinv[node];
    float acc[8];
    {
        uint4 v = *reinterpret_cast<const uint4*>(hb + (size_t)node * D + sl * 8);
        float w = dn * dn;
        acc[0] = w * blo(v.x); acc[1] = w * bhi(v.x);
        acc[2] = w * blo(v.y); acc[3] = w * bhi(v.y);
        acc[4] = w * blo(v.z); acc[5] = w * bhi(v.z);
        acc[6] = w * blo(v.w); acc[7] = w * bhi(v.w);
    }
    int j = rowptr[node];
    const int end = rowptr[node + 1];
    while ((j & 3) && j < end) {
        int s = csr16[j];
        uint4 g = *reinterpret_cast<const uint4*>(hb + (size_t)s * D + sl * 8);
        fma8(dn * dinv[s], g, acc);
        ++j;
    }
    for (; j + 4 <= end; j += 4) {
        ushort4 q = *reinterpret_cast<const ushort4*>(csr16 + j);
        uint4 g0 = *reinterpret_cast<const uint4*>(hb + (size_t)q.x * D + sl * 8);
        uint4 g1 = *reinterpret_cast<const uint4*>(hb + (size_t)q.y * D + sl * 8);
        uint4 g2 = *reinterpret_cast<const uint4*>(hb + (size_t)q.z * D + sl * 8);
        uint4 g3 = *reinterpret_cast<const uint4*>(hb + (size_t)q.w * D + sl * 8);
        float w0 = dn * dinv[q.x], w1 = dn * dinv[q.y];
        float w2 = dn * dinv[q.z], w3 = dn * dinv[q.w];
        fma8(w0, g0, acc);
        fma8(w1, g1, acc);
        fma8(w2, g2, acc);
        fma8(w3, g3, acc);
    }
    while (j < end) {
        int s = csr16[j];
        uint4 g = *reinterpret_cast<const uint4*>(hb + (size_t)s * D + sl * 8);
        fma8(dn * dinv[s], g, acc);
        ++j;
    }
    if (BIAS_RELU) {
        float4 b0 = *reinterpret_cast<const float4*>(bias + sl * 8);
        float4 b1v = *reinterpret_cast<const float4*>(bias + sl * 8 + 4);
        acc[0] = fmaxf(acc[0] + b0.x, 0.f); acc[1] = fmaxf(acc[1] + b0.y, 0.f);
        acc[2] = fmaxf(acc[2] + b0.z, 0.f); acc[3] = fmaxf(acc[3] + b0.w, 0.f);
        acc[4] = fmaxf(acc[4] + b1v.x, 0.f); acc[5] = fmaxf(acc[5] + b1v.y, 0.f);
        acc[6] = fmaxf(acc[6] + b1v.z, 0.f); acc[7] = fmaxf(acc[7] + b1v.w, 0.f);
    }
    uint4 o;
    o.x = f2b(acc[0]) | (f2b(acc[1]) << 16);
    o.y = f2b(acc[2]) | (f2b(acc[3]) << 16);
    o.z = f2b(acc[4]) | (f2b(acc[5]) << 16);
    o.w = f2b(acc[6]) | (f2b(acc[7]) << 16);
    *reinterpret_cast<uint4*>(reinterpret_cast<ushort*>(out) + (size_t)node * D + sl * 8) = o;
}

// ---------------- MFMA fused double GEMM (unchanged from round 22) ----------------
__global__ __launch_bounds__(256) void k_gemm12m(const ushort* __restrict__ A,
                                                 const ushort* __restrict__ w1bt,
                                                 const float* __restrict__ b1,
                                                 const ushort* __restrict__ w2bt,
                                                 ushort* __restrict__ T) {
    constexpr int HP = 136;             // sH row stride (ushorts), pad kills bank conflicts
    __shared__ ushort sH[4 * 16 * HP];  // 17408 B
    const int t = threadIdx.x;
    const int w = t >> 6;        // wave 0..3
    const int l = t & 63;        // lane
    const int r16 = l & 15;      // fragment 16-dim index
    const int kg = l >> 4;       // k-group 0..3
    const int row0 = blockIdx.x * 64 + w * 16;
    ushort* sHw = &sH[w * 16 * HP];

    // ---- A fragments for GEMM1 (rows from agg1b, clamped for tail block)
    bf16x8 a1_0, a1_1;
    {
        int gr = row0 + r16;
        const ushort* Ap = A + (size_t)(gr < NN ? gr : NN - 1) * DI + kg * 8;
        a1_0 = *reinterpret_cast<const bf16x8*>(Ap);
        a1_1 = *reinterpret_cast<const bf16x8*>(Ap + 32);
    }

    // ---- GEMM1: 8 col-tiles of 16, K=64 (2 MFMA each), +b1, relu -> sH
#pragma unroll
    for (int ct = 0; ct < 8; ++ct) {
        const ushort* Bp = w1bt + (size_t)(ct * 16 + r16) * DI + kg * 8;
        bf16x8 b0 = *reinterpret_cast<const bf16x8*>(Bp);
        bf16x8 bq = *reinterpret_cast<const bf16x8*>(Bp + 32);
        f32x4 c = {0.f, 0.f, 0.f, 0.f};
        c = __builtin_amdgcn_mfma_f32_16x16x32_bf16(a1_0, b0, c, 0, 0, 0);
        c = __builtin_amdgcn_mfma_f32_16x16x32_bf16(a1_1, bq, c, 0, 0, 0);
        float bb = b1[ct * 16 + r16];
#pragma unroll
        for (int r = 0; r < 4; ++r) {
            float v = fmaxf(c[r] + bb, 0.f);
            sHw[(kg * 4 + r) * HP + ct * 16 + r16] = (ushort)f2b(v);
        }
    }
    __syncthreads();

    // ---- A fragments for GEMM2 from sH (conflict-free b128 via pad-136)
    bf16x8 a2_0 = *reinterpret_cast<const bf16x8*>(&sHw[r16 * HP + 0 * 32 + kg * 8]);
    bf16x8 a2_1 = *reinterpret_cast<const bf16x8*>(&sHw[r16 * HP + 1 * 32 + kg * 8]);
    bf16x8 a2_2 = *reinterpret_cast<const bf16x8*>(&sHw[r16 * HP + 2 * 32 + kg * 8]);
    bf16x8 a2_3 = *reinterpret_cast<const bf16x8*>(&sHw[r16 * HP + 3 * 32 + kg * 8]);

    // ---- GEMM2: 8 col-tiles, K=128 (4 MFMA each) -> tb bf16
#pragma unroll
    for (int ct = 0; ct < 8; ++ct) {
        const ushort* Bp = w2bt + (size_t)(ct * 16 + r16) * DH + kg * 8;
        bf16x8 b0 = *reinterpret_cast<const bf16x8*>(Bp);
        bf16x8 b1v = *reinterpret_cast<const bf16x8*>(Bp + 32);
        bf16x8 b2v = *reinterpret_cast<const bf16x8*>(Bp + 64);
        bf16x8 b3v = *reinterpret_cast<const bf16x8*>(Bp + 96);
        f32x4 c = {0.f, 0.f, 0.f, 0.f};
        c = __builtin_amdgcn_mfma_f32_16x16x32_bf16(a2_0, b0, c, 0, 0, 0);
        c = __builtin_amdgcn_mfma_f32_16x16x32_bf16(a2_1, b1v, c, 0, 0, 0);
        c = __builtin_amdgcn_mfma_f32_16x16x32_bf16(a2_2, b2v, c, 0, 0, 0);
        c = __builtin_amdgcn_mfma_f32_16x16x32_bf16(a2_3, b3v, c, 0, 0, 0);
#pragma unroll
        for (int r = 0; r < 4; ++r) {
            int gr = row0 + kg * 4 + r;
            if (gr < NN)
                T[(size_t)gr * DH + ct * 16 + r16] = (ushort)f2b(c[r]);
        }
    }
}

// ---------------- pooling (bf16 input, coalesced u32 reads) ----------------
constexpr int POOL_CHUNK = 64;
__global__ __launch_bounds__(256) void k_pool3(const u32* __restrict__ h2b,
                                               const int* __restrict__ batch,
                                               float* __restrict__ pooled) {
    const int c2 = threadIdx.x & 63;
    const int q = threadIdx.x >> 6;
    const int n0 = blockIdx.x * POOL_CHUNK;
    const int nEnd = min(n0 + POOL_CHUNK, NN);
    float a0 = 0.f, a1 = 0.f;
    int gcur = -1;
    for (int n = n0 + q; n < nEnd; n += 4) {
        int g = batch[n];
        if (g != gcur) {
            if (gcur >= 0) {
                atomicAdd(&pooled[gcur * DH + c2 * 2], a0);
                atomicAdd(&pooled[gcur * DH + c2 * 2 + 1], a1);
            }
            a0 = a1 = 0.f;
            gcur = g;
        }
        u32 v = h2b[(size_t)n * (DH / 2) + c2];
        a0 += blo(v);
        a1 += bhi(v);
    }
    if (gcur >= 0) {
        atomicAdd(&pooled[gcur * DH + c2 * 2], a0);
        atomicAdd(&pooled[gcur * DH + c2 * 2 + 1], a1);
    }
}

__global__ void k_head(const float* __restrict__ pooled, const int* __restrict__ gstart,
                       const float* __restrict__ Wf, const float* __restrict__ bf,
                       float* __restrict__ out) {
    int t = threadIdx.x;
    if (t >= NG * DO) return;
    int g = t / DO, o = t - g * DO;
    float acc = 0.0f;
    for (int k = 0; k < DH; ++k) acc += pooled[g * DH + k] * Wf[k * DO + o];
    float cnt = fmaxf((float)(gstart[g + 1] - gstart[g]), 1.0f);
    out[t] = acc / cnt + bf[o];
}

extern "C" void kernel_launch(void* const* d_in, const int* in_sizes, int n_in,
                              void* d_out, int out_size, void* d_ws, size_t ws_size,
                              hipStream_t stream) {
    const float* x   = (const float*)d_in[0];
    const int* ei    = (const int*)d_in[1];  // [2, NE] row-major
    const int* batch = (const int*)d_in[2];
    const float* W1  = (const float*)d_in[3];
    const float* b1  = (const float*)d_in[4];
    const float* W2  = (const float*)d_in[5];
    const float* b2  = (const float*)d_in[6];
    const float* Wf  = (const float*)d_in[7];
    const float* bf  = (const float*)d_in[8];
    float* out = (float*)d_out;

    const int* src = ei;
    const int* dst = ei + NE;

    // workspace (4B units; ~44 MB total)
    int* rowptr    = (int*)d_ws;               // 50056 (NN+1 used)
    int* bbpartial = rowptr + 50056;           // 256
    int* gstart    = bbpartial + 256;          // 80
    int* cntBB     = gstart + 80;              // 38416 ([b][c] bucket-major)
    ushort* csr16  = (ushort*)(cntBB + 38416); // NE u16 = 400000 u32
    float* dinv    = (float*)((u32*)(cntBB + 38416) + 400000);  // 50048
    u32* xbu       = (u32*)(dinv + 50048);     // 1.6M u32 (NN x 64 bf16)
    u32* stage     = xbu + 1600000;            // 0.8M u32 (NE packed entries)
    u32* agg1bu    = stage + 800000;           // 1.6M u32 (NN x 64 bf16)
    u32* tbu       = agg1bu + 1600000;         // 3.2M u32 (NN x 128 bf16)
    u32* h2b       = tbu + 3200000;            // 3.2M u32 (NN x 128 bf16)
    float* pooled  = (float*)(h2b + 3200000);  // 8192
    ushort* w1bt   = (ushort*)(pooled + 8192); // 8192 ushort (W1^T bf16 [128][64])
    ushort* w2bt   = w1bt + 8192;              // 16384 ushort (W2^T bf16 [128][128])

    ushort* xb    = (ushort*)xbu;
    ushort* agg1b = (ushort*)agg1bu;
    ushort* tb    = (ushort*)tbu;

    const int B = 256;
    // fused init + histc (blocks < NCH do the edge histogram)
    k_init<<<(NN * DI / 8 + B - 1) / B, B, 0, stream>>>(x, (uint4*)xb, pooled, batch,
                                                        gstart, W1, W2, w1bt, w2bt,
                                                        dst, cntBB);
    k_scanBB1<<<NBB, SCAN_B, 0, stream>>>(cntBB, bbpartial);
    k_fillP2<<<NCH, 256, 0, stream>>>(src, dst, cntBB, bbpartial, stage);
    k_fillB<<<NBK, 256, 0, stream>>>(stage, cntBB, bbpartial, rowptr, dinv, csr16);

    // layer 1 agg (zero-LDS, high occupancy): gather xb -> agg1b bf16
    k_agge<DI, false><<<(NN + 31) / 32, 256, 0, stream>>>(xb, csr16, rowptr, dinv,
                                                          nullptr, agg1bu);
    // MFMA fused GEMM1+GEMM2: agg1b -> h1 (LDS bf16) -> tb
    k_gemm12m<<<(NN + 63) / 64, 256, 0, stream>>>(agg1b, w1bt, b1, w2bt, tb);

    // layer-2 agg: gather tb, +b2, relu -> h2b (bf16)
    k_agge<DH, true><<<(NN + 15) / 16, 256, 0, stream>>>(tb, csr16, rowptr, dinv, b2, h2b);

    // pool + head
    k_pool3<<<(NN + POOL_CHUNK - 1) / POOL_CHUNK, 256, 0, stream>>>(h2b, batch, pooled);
    k_head<<<1, 256, 0, stream>>>(pooled, gstart, Wf, bf, out);
}